// Round 15
// baseline (307.524 us; speedup 1.0000x reference)
//
#include <hip/hip_runtime.h>
#include <math.h>

#define BATCH 64
#define SLATES 25
#define KPS 20
#define EDIM 256
#define DDIM 512
#define HEADS 8
#define HD 64
#define LFULL 501
#define NROWS 500
#define MTOT (BATCH*NROWS)   // 32000
#define CMAX 512
#define NQKV 1536
#define RB 32
#define NRB ((NROWS + RB - 1) / RB)   // 16

// prep_light block ranges (uniform light blocks only)
#define NCVT  8000
#define NPACK 384
#define NWO   256
#define NW1P  128
#define PREP_TOTAL (NCVT + NPACK + NWO + NW1P)   // 8768

typedef __attribute__((ext_vector_type(8))) short short8;
typedef __attribute__((ext_vector_type(4))) float f32x4;

__device__ __forceinline__ unsigned short f2bf(float x) {
    unsigned int u = __builtin_bit_cast(unsigned int, x);
    u = (u + 0x7FFFu + ((u >> 16) & 1u)) >> 16;
    return (unsigned short)u;
}
__device__ __forceinline__ float bf2f(unsigned short s) {
    unsigned int u = ((unsigned int)s) << 16;
    return __builtin_bit_cast(float, u);
}
__device__ __forceinline__ float gelu_exact(float x) {
    return 0.5f * x * (1.0f + erff(x * 0.70710678118654752440f));
}
__device__ __forceinline__ void gload16(const void* g, void* l) {
    __builtin_amdgcn_global_load_lds(
        (const __attribute__((address_space(1))) void*)g,
        (__attribute__((address_space(3))) void*)l, 16, 0, 0);
}

// ---------------------------------------------------------------------------
// Fused light prep: item cvt / Wqkv pack / Wo cvt / W1g prep.
// ---------------------------------------------------------------------------
struct PrepArgs {
    const float* item;
    const float* Wq; const float* Wk; const float* Wv;
    const float* Wo; const float* W1;
    const float* lng; const float* lnb;
    unsigned short* itemb; unsigned short* Wqkvb; unsigned short* Wob;
    unsigned short* W1gb; float2* c1c2;
};

__global__ __launch_bounds__(256) void prep_light(PrepArgs a)
{
    const int bid = blockIdx.x;
    const int tid = threadIdx.x;

    if (bid < NCVT) {
        const int i = bid * 256 + tid;
        float4 v = ((const float4*)a.item)[i];
        ushort4 o;
        o.x = f2bf(v.x); o.y = f2bf(v.y); o.z = f2bf(v.z); o.w = f2bf(v.w);
        ((ushort4*)a.itemb)[i] = o;
        return;
    }
    if (bid < NCVT + NPACK) {
        const int idx = bid - NCVT;
        const int y = idx / 128;
        const float* W = (y == 0) ? a.Wq : (y == 1) ? a.Wk : a.Wv;
        const int i = (idx % 128) * 256 + tid;
        const int row = i >> 6, c4 = (i & 63) * 4;
        float4 v = *(const float4*)&W[(size_t)row * DDIM + c4];
        ushort4 o;
        o.x = f2bf(v.x); o.y = f2bf(v.y); o.z = f2bf(v.z); o.w = f2bf(v.w);
        *(ushort4*)&a.Wqkvb[((size_t)y * DDIM + row) * EDIM + c4] = o;
        return;
    }
    if (bid < NCVT + NPACK + NWO) {
        const int i = (bid - NCVT - NPACK) * 256 + tid;
        float4 v = ((const float4*)a.Wo)[i];
        ushort4 o;
        o.x = f2bf(v.x); o.y = f2bf(v.y); o.z = f2bf(v.z); o.w = f2bf(v.w);
        ((ushort4*)a.Wob)[i] = o;
        return;
    }
    {
        const int row = (bid - NCVT - NPACK - NWO) * 4 + (tid >> 6);
        const int lane = tid & 63;
        float c1 = 0.f, c2 = 0.f;
#pragma unroll
        for (int i = 0; i < 8; ++i) {
            const int k = lane + i * 64;
            const float w = a.W1[(size_t)row * DDIM + k];
            const float gv = a.lng[k];
            c1 += w * a.lnb[k];
            c2 += w * gv;
            a.W1gb[(size_t)row * DDIM + k] = f2bf(w * gv);
        }
#pragma unroll
        for (int off = 32; off; off >>= 1) {
            c1 += __shfl_xor(c1, off, 64);
            c2 += __shfl_xor(c2, off, 64);
        }
        if (lane == 0) a.c1c2[row] = make_float2(c1, c2);
    }
}

// ---------------------------------------------------------------------------
// Click compaction: one wave per batch.
// ---------------------------------------------------------------------------
__global__ __launch_bounds__(64) void compact_kernel(
    const int* __restrict__ resp, int* __restrict__ cidx, int* __restrict__ cnt)
{
    const int b = blockIdx.x, lane = threadIdx.x;
    int a[8]; int c = 0;
#pragma unroll
    for (int j = 0; j < 8; ++j) {
        const int l = lane * 8 + j;
        int al = 0;
        if (l == 0) al = 1;
        else if (l <= NROWS) al = (resp[(size_t)b * NROWS + l - 1] > 0) ? 1 : 0;
        a[j] = al; c += al;
    }
    int incl = c;
#pragma unroll
    for (int off = 1; off < 64; off <<= 1) {
        int t = __shfl_up(incl, off, 64);
        if (lane >= off) incl += t;
    }
    int run = incl - c;
#pragma unroll
    for (int j = 0; j < 8; ++j) {
        const int l = lane * 8 + j;
        if (l >= 1 && l <= 481 && (l % 20) == 1)
            cnt[b * 32 + (l - 1) / 20] = run;
        cidx[b * 512 + l] = a[j] ? run : -1;
        run += a[j];
    }
}

// ---------------------------------------------------------------------------
// User bias, coalesced: wave-per-output-row, 4 coalesced 64-lane reads,
// shfl reduce. grid (BATCH, 3).
// ---------------------------------------------------------------------------
__global__ __launch_bounds__(256) void user_bias_kernel(
    const float* __restrict__ user,
    const float* __restrict__ Wq, const float* __restrict__ bq,
    const float* __restrict__ Wk, const float* __restrict__ bk,
    const float* __restrict__ Wv, const float* __restrict__ bv,
    float* __restrict__ uball,
    unsigned short* __restrict__ qb, unsigned short* __restrict__ kc,
    unsigned short* __restrict__ vc)
{
    const int b = blockIdx.x, y = blockIdx.y;
    const int tid = threadIdx.x, lane = tid & 63, w = tid >> 6;
    const float* W  = (y == 0) ? Wq : (y == 1) ? Wk : Wv;
    const float* bi = (y == 0) ? bq : (y == 1) ? bk : bv;

    __shared__ float us[EDIM];
    if (tid < EDIM) us[tid] = user[b * EDIM + tid];
    __syncthreads();

    float ul[4];
#pragma unroll
    for (int i = 0; i < 4; ++i) ul[i] = us[lane + i * 64];

    for (int o = w; o < DDIM; o += 4) {
        const float* wr = &W[(size_t)o * DDIM + EDIM];
        float s = 0.f;
#pragma unroll
        for (int i = 0; i < 4; ++i) s += ul[i] * wr[lane + i * 64];
#pragma unroll
        for (int off = 32; off; off >>= 1) s += __shfl_xor(s, off, 64);
        if (lane == 0) {
            uball[(size_t)b * NQKV + y * DDIM + o] = s + bi[o];
            const int hh = o >> 6, dd = o & 63;
            const size_t bh = (size_t)b * HEADS + hh;
            if (y == 0)      qb[(bh * LFULL) * HD + dd] = f2bf(bi[o]);
            else if (y == 1) kc[(bh * CMAX) * HD + dd] = f2bf(bi[o]);
            else             vc[(bh * HD + dd) * CMAX] = f2bf(bi[o]);
        }
    }
}

// ---------------------------------------------------------------------------
// Merged QKV GEMM: counted-vmcnt 3-buffer pipeline + LDS-bounce coalesced
// epilogue + XCD-chunked block swizzle. Grid = (12, 250) = 3000 blocks.
// ---------------------------------------------------------------------------
__global__ __launch_bounds__(256) void gemm_qkv(
    const unsigned short* __restrict__ A,
    const unsigned short* __restrict__ Wqkv,
    const float* __restrict__ uball, const int* __restrict__ cidx,
    unsigned short* __restrict__ oq, unsigned short* __restrict__ ok,
    unsigned short* __restrict__ ov)
{
    const int tid = threadIdx.x;
    const int lin = blockIdx.y * gridDim.x + blockIdx.x;
    const int vb  = (lin & 7) * 375 + (lin >> 3);
    const int n0 = (vb % 12) * 128;   // 0..1535
    const int m0 = (vb / 12) * 128;
    const int lane = tid & 63, wid = tid >> 6;
    const int wm = (wid & 1) * 64, wn = (wid >> 1) * 64;

    __shared__ __align__(16) unsigned short sm[24576];
    __shared__ int cids[128];
    auto As = [&](int buf) { return (unsigned short(*)[32])(sm + buf * 4096); };
    auto Ws = [&](int buf) { return (unsigned short(*)[32])(sm + 12288 + buf * 4096); };
    auto bounce = (unsigned short(*)[136])sm;

    f32x4 acc[4][4];
#pragma unroll
    for (int i = 0; i < 4; ++i)
#pragma unroll
        for (int j = 0; j < 4; ++j) acc[i][j] = (f32x4){0.f, 0.f, 0.f, 0.f};

    const unsigned short* gA0 = &A[(size_t)(m0 + wid * 16 + (lane >> 2)) * EDIM + (lane & 3) * 8];
    const unsigned short* gA1 = gA0 + (size_t)64 * EDIM;
    const unsigned short* gW0 = &Wqkv[(size_t)(n0 + wid * 16 + (lane >> 2)) * EDIM + (lane & 3) * 8];
    const unsigned short* gW1 = gW0 + (size_t)64 * EDIM;
    const int frow = lane & 15, fk = (lane >> 4) * 8;

    auto stage = [&](int buf, int k0) {
        gload16(gA0 + k0, &As(buf)[wid * 16][0]);
        gload16(gA1 + k0, &As(buf)[64 + wid * 16][0]);
        gload16(gW0 + k0, &Ws(buf)[wid * 16][0]);
        gload16(gW1 + k0, &Ws(buf)[64 + wid * 16][0]);
    };
    stage(0, 0);
    stage(1, 32);

    const int nst = EDIM / 32;   // 8
    for (int t = 0; t < nst; ++t) {
        const int cur = t % 3;
        if (t < nst - 1) asm volatile("s_waitcnt vmcnt(4)" ::: "memory");
        else             asm volatile("s_waitcnt vmcnt(0)" ::: "memory");
        __builtin_amdgcn_s_barrier();
        __builtin_amdgcn_sched_barrier(0);
        short8 af[4], wf[4];
#pragma unroll
        for (int mi = 0; mi < 4; ++mi)
            af[mi] = *(const short8*)&As(cur)[wm + mi * 16 + frow][fk];
#pragma unroll
        for (int ni = 0; ni < 4; ++ni)
            wf[ni] = *(const short8*)&Ws(cur)[wn + ni * 16 + frow][fk];
#pragma unroll
        for (int mi = 0; mi < 4; ++mi)
#pragma unroll
            for (int ni = 0; ni < 4; ++ni)
                acc[mi][ni] = __builtin_amdgcn_mfma_f32_16x16x32_bf16(
                    af[mi], wf[ni], acc[mi][ni], 0, 0, 0);
        if (t + 2 < nst) stage((t + 2) % 3, (t + 2) * 32);
    }

    // ---- epilogue: bounce through LDS for coalesced stores ----
    const int z = n0 >> 9;               // 0=q 1=k 2=v
    const int b0 = m0 / NROWS;
    const int split = (b0 + 1) * NROWS;
    const int b1 = (split <= m0 + 127) ? b0 + 1 : b0;
    float ub0[4], ub1[4];
#pragma unroll
    for (int ni = 0; ni < 4; ++ni) {
        const int np = n0 + wn + ni * 16 + frow;
        ub0[ni] = uball[(size_t)b0 * NQKV + np];
        ub1[ni] = uball[(size_t)b1 * NQKV + np];
    }
    __syncthreads();
    if (z != 0 && tid < 128) {
        const int m = m0 + tid;
        const int b = (m >= split) ? b1 : b0;
        cids[tid] = cidx[b * 512 + (m - b * NROWS + 1)];
    }
#pragma unroll
    for (int mi = 0; mi < 4; ++mi)
#pragma unroll
        for (int r = 0; r < 4; ++r) {
            const int ml = wm + mi * 16 + (lane >> 4) * 4 + r;
            const bool hi = (m0 + ml >= split);
#pragma unroll
            for (int ni = 0; ni < 4; ++ni)
                bounce[ml][wn + ni * 16 + frow] =
                    f2bf(acc[mi][ni][r] + (hi ? ub1[ni] : ub0[ni]));
        }
    __syncthreads();

    const int h0 = (n0 & 511) >> 6;
    if (z == 0) {
        const int row = tid >> 1, half = tid & 1;
        const int m = m0 + row;
        const int b = (m >= split) ? b1 : b0;
        const int l = m - b * NROWS + 1;
        unsigned short* dst = &oq[(((size_t)b * HEADS + h0 + half) * LFULL + l) * HD];
        const unsigned short* src = &bounce[row][half * 64];
#pragma unroll
        for (int j = 0; j < 8; ++j)
            *(uint4*)(dst + j * 8) = *(const uint4*)(src + j * 8);
    } else if (z == 1) {
        const int row = tid >> 1, half = tid & 1;
        const int c = cids[row];
        if (c >= 0) {
            const int m = m0 + row;
            const int b = (m >= split) ? b1 : b0;
            unsigned short* dst = &ok[(((size_t)b * HEADS + h0 + half) * CMAX + c) * HD];
            const unsigned short* src = &bounce[row][half * 64];
#pragma unroll
            for (int j = 0; j < 8; ++j)
                *(uint4*)(dst + j * 8) = *(const uint4*)(src + j * 8);
        }
    } else {
        const int col = tid & 127, mh = tid >> 7;
        const int hh = h0 + (col >> 6), dd = col & 63;
        for (int mm = 0; mm < 64; ++mm) {
            const int row = mh * 64 + mm;
            const int c = cids[row];
            if (c >= 0) {
                const int m = m0 + row;
                const int b = (m >= split) ? b1 : b0;
                ov[((size_t)b * HEADS + hh) * (size_t)(HD * CMAX)
                   + (size_t)dd * CMAX + c] = bounce[row][col];
            }
        }
    }
}

// ---------------------------------------------------------------------------
// Generic bf16 GEMM (counted-vmcnt 3-buffer) + XCD swizzle (1000 = 8 x 125).
// MODE 1 (Wo): +bias, bf16 out, per-row partial (sum f, sum f^2) -> rowpart.
// MODE 2 (W1g): inline LN stats from rowpart, LN-folded gelu + W2 dot.
// ---------------------------------------------------------------------------
template <int MODE>
__global__ __launch_bounds__(256) void gemm_bf16(
    const unsigned short* __restrict__ A,
    const unsigned short* __restrict__ W,
    const float* __restrict__ bias, void* __restrict__ outp,
    const float* __restrict__ W2, float* __restrict__ part,
    const float* __restrict__ rowpart, const float2* __restrict__ c1c2)
{
    const int tid = threadIdx.x;
    const int lin = blockIdx.y * gridDim.x + blockIdx.x;
    const int vb  = (lin & 7) * 125 + (lin >> 3);
    const int n0 = (vb % 4) * 128;
    const int m0 = (vb / 4) * 128;
    const int lane = tid & 63, wid = tid >> 6;
    const int wm = (wid & 1) * 64, wn = (wid >> 1) * 64;

    __shared__ unsigned short As[3][128][32];
    __shared__ unsigned short Ws[3][128][32];
    __shared__ float2 smusr[128];

    f32x4 acc[4][4];
#pragma unroll
    for (int i = 0; i < 4; ++i)
#pragma unroll
        for (int j = 0; j < 4; ++j) acc[i][j] = (f32x4){0.f, 0.f, 0.f, 0.f};

    const unsigned short* gA0 = &A[(size_t)(m0 + wid * 16 + (lane >> 2)) * DDIM + (lane & 3) * 8];
    const unsigned short* gA1 = gA0 + (size_t)64 * DDIM;
    const unsigned short* gW0 = &W[(size_t)(n0 + wid * 16 + (lane >> 2)) * DDIM + (lane & 3) * 8];
    const unsigned short* gW1 = gW0 + (size_t)64 * DDIM;
    const int frow = lane & 15, fk = (lane >> 4) * 8;

    auto stage = [&](int buf, int k0) {
        gload16(gA0 + k0, &As[buf][wid * 16][0]);
        gload16(gA1 + k0, &As[buf][64 + wid * 16][0]);
        gload16(gW0 + k0, &Ws[buf][wid * 16][0]);
        gload16(gW1 + k0, &Ws[buf][64 + wid * 16][0]);
    };
    stage(0, 0);
    stage(1, 32);

    const int nst = DDIM / 32;   // 16
    for (int t = 0; t < nst; ++t) {
        const int cur = t % 3;
        if (t < nst - 1) asm volatile("s_waitcnt vmcnt(4)" ::: "memory");
        else             asm volatile("s_waitcnt vmcnt(0)" ::: "memory");
        __builtin_amdgcn_s_barrier();
        __builtin_amdgcn_sched_barrier(0);
        short8 af[4], wf[4];
#pragma unroll
        for (int mi = 0; mi < 4; ++mi)
            af[mi] = *(const short8*)&As[cur][wm + mi * 16 + frow][fk];
#pragma unroll
        for (int ni = 0; ni < 4; ++ni)
            wf[ni] = *(const short8*)&Ws[cur][wn + ni * 16 + frow][fk];
#pragma unroll
        for (int mi = 0; mi < 4; ++mi)
#pragma unroll
            for (int ni = 0; ni < 4; ++ni)
                acc[mi][ni] = __builtin_amdgcn_mfma_f32_16x16x32_bf16(
                    af[mi], wf[ni], acc[mi][ni], 0, 0, 0);
        if (t + 2 < nst) stage((t + 2) % 3, (t + 2) * 32);
    }

    const int slot = (n0 >> 7) * 2 + (wn >> 6);   // 0..7
    if (MODE == 1) {
        float bv4[4];
#pragma unroll
        for (int ni = 0; ni < 4; ++ni) bv4[ni] = bias[n0 + wn + ni * 16 + frow];
#pragma unroll
        for (int mi = 0; mi < 4; ++mi)
#pragma unroll
            for (int r = 0; r < 4; ++r) {
                const int m = m0 + wm + mi * 16 + (lane >> 4) * 4 + r;
                float s1 = 0.f, s2 = 0.f;
#pragma unroll
                for (int ni = 0; ni < 4; ++ni) {
                    const float v = acc[mi][ni][r] + bv4[ni];
                    s1 += v; s2 += v * v;
                    ((unsigned short*)outp)[(size_t)m * DDIM + n0 + wn + ni * 16 + frow]
                        = f2bf(v);
                }
                s1 += __shfl_xor(s1, 1, 64); s2 += __shfl_xor(s2, 1, 64);
                s1 += __shfl_xor(s1, 2, 64); s2 += __shfl_xor(s2, 2, 64);
                s1 += __shfl_xor(s1, 4, 64); s2 += __shfl_xor(s2, 4, 64);
                s1 += __shfl_xor(s1, 8, 64); s2 += __shfl_xor(s2, 8, 64);
                if (frow == 0) {
                    part[((size_t)m << 4) + slot * 2]     = s1;
                    part[((size_t)m << 4) + slot * 2 + 1] = s2;
                }
            }
    } else {
        if (tid < 128) {
            const float* pp = rowpart + ((size_t)(m0 + tid) << 4);
            float s1 = 0.f, s2 = 0.f;
#pragma unroll
            for (int i = 0; i < 8; ++i) { s1 += pp[i * 2]; s2 += pp[i * 2 + 1]; }
            const float mu = s1 * (1.0f / DDIM);
            const float var = s2 * (1.0f / DDIM) - mu * mu;
            smusr[tid] = make_float2(mu, rsqrtf(var + 1e-5f));
        }
        float w2v[4], cb[4], c2v[4];
#pragma unroll
        for (int ni = 0; ni < 4; ++ni) {
            const int n = n0 + wn + ni * 16 + frow;
            w2v[ni] = W2[n];
            const float2 cc = c1c2[n];
            cb[ni]  = cc.x + bias[n];
            c2v[ni] = cc.y;
        }
        __syncthreads();
#pragma unroll
        for (int mi = 0; mi < 4; ++mi)
#pragma unroll
            for (int r = 0; r < 4; ++r) {
                const int ml = wm + mi * 16 + (lane >> 4) * 4 + r;
                const float2 ms = smusr[ml];
                float s = 0.f;
#pragma unroll
                for (int ni = 0; ni < 4; ++ni)
                    s += gelu_exact(ms.y * (acc[mi][ni][r] - ms.x * c2v[ni]) + cb[ni])
                         * w2v[ni];
                s += __shfl_xor(s, 1, 64);
                s += __shfl_xor(s, 2, 64);
                s += __shfl_xor(s, 4, 64);
                s += __shfl_xor(s, 8, 64);
                if (frow == 0)
                    part[(size_t)(m0 + ml) * 8 + slot] = s;
            }
    }
}

// ---------------------------------------------------------------------------
// Final reduction: out[m] = b2 + sum of 8 partials.
// ---------------------------------------------------------------------------
__global__ __launch_bounds__(256) void w2red_kernel(
    const float* __restrict__ part, const float* __restrict__ b2,
    float* __restrict__ out)
{
    const int m = blockIdx.x * 256 + threadIdx.x;
    if (m >= MTOT) return;
    const float* p = part + (size_t)m * 8;
    float s = b2[0];
#pragma unroll
    for (int i = 0; i < 8; ++i) s += p[i];
    out[m] = s;
}

// ---------------------------------------------------------------------------
// Attention v7: row-packed 32-row blocks, per-row key-count mask, fused exp,
// XCD-chunked swizzle (8192 = 8 x 1024).
// ---------------------------------------------------------------------------
__global__ __launch_bounds__(256) void attn_mfma(
    const unsigned short* __restrict__ qx, const unsigned short* __restrict__ kc,
    const unsigned short* __restrict__ vc, const int* __restrict__ cnt,
    unsigned short* __restrict__ outb)
{
    const int lin = blockIdx.x + NRB * (blockIdx.y + HEADS * blockIdx.z);
    const int vbk = (lin & 7) * (NRB * HEADS * BATCH / 8) + (lin >> 3);
    const int rbk = vbk % NRB;
    const int h   = (vbk / NRB) % HEADS;
    const int b   = vbk / (NRB * HEADS);
    const int g0  = rbk * RB;

    const int tid = threadIdx.x, lane = tid & 63, w = tid >> 6;

    __shared__ __align__(16) unsigned short scb[RB][520];
    __shared__ float rsw[4][RB];
    __shared__ int snck[RB];

    const int frow = lane & 15, fk = (lane >> 4) * 8;
    const size_t bh = (size_t)b * HEADS + h;
    const unsigned short* kbase = kc + bh * (CMAX * HD);
    const unsigned short* vbase = vc + bh * (HD * CMAX);

    if (tid < RB) {
        const int s = (g0 + tid >= NROWS ? NROWS - 1 : g0 + tid) / KPS;
        snck[tid] = cnt[b * 32 + s];
    }

    short8 qf[2][2];
#pragma unroll
    for (int mi = 0; mi < 2; ++mi) {
        const int qrow = g0 + mi * 16 + frow;
#pragma unroll
        for (int ks = 0; ks < 2; ++ks) {
            short8 v = {};
            if (qrow < NROWS)
                v = *(const short8*)&qx[(bh * LFULL + qrow + 1) * HD + ks * 32 + fk];
            qf[mi][ks] = v;
        }
    }
    __syncthreads();

    int nck8[2][4];
#pragma unroll
    for (int mi = 0; mi < 2; ++mi)
#pragma unroll
        for (int r = 0; r < 4; ++r)
            nck8[mi][r] = snck[mi * 16 + (lane >> 4) * 4 + r];
    const int nmax = snck[RB - 1];
    const int NT = (nmax + 63) >> 6;

    f32x4 rsum[2];
    rsum[0] = (f32x4){0.f, 0.f, 0.f, 0.f};
    rsum[1] = (f32x4){0.f, 0.f, 0.f, 0.f};
    for (int t = 0; t < NT; ++t) {
        const int key = (t << 6) + w * 16 + frow;
        const unsigned short* kr = kbase + (size_t)key * HD;
        const short8 kf0 = *(const short8*)(kr + fk);
        const short8 kf1 = *(const short8*)(kr + 32 + fk);
        f32x4 s2[2];
#pragma unroll
        for (int mi = 0; mi < 2; ++mi) {
            s2[mi] = (f32x4){0.f, 0.f, 0.f, 0.f};
            s2[mi] = __builtin_amdgcn_mfma_f32_16x16x32_bf16(qf[mi][0], kf0, s2[mi], 0, 0, 0);
            s2[mi] = __builtin_amdgcn_mfma_f32_16x16x32_bf16(qf[mi][1], kf1, s2[mi], 0, 0, 0);
        }
#pragma unroll
        for (int mi = 0; mi < 2; ++mi)
#pragma unroll
            for (int r = 0; r < 4; ++r) {
                const int row = mi * 16 + (lane >> 4) * 4 + r;
                const float p = (key < nck8[mi][r]) ? __expf(s2[mi][r] * 0.125f) : 0.f;
                rsum[mi][r] += p;
                scb[row][key] = f2bf(p);
            }
    }
#pragma unroll
    for (int mi = 0; mi < 2; ++mi)
#pragma unroll
        for (int r = 0; r < 4; ++r) {
            float v = rsum[mi][r];
            v += __shfl_xor(v, 1, 64);
            v += __shfl_xor(v, 2, 64);
            v += __shfl_xor(v, 4, 64);
            v += __shfl_xor(v, 8, 64);
            if (frow == 0)
                rsw[w][mi * 16 + (lane >> 4) * 4 + r] = v;
        }
    __syncthreads();

    f32x4 po[2];
    po[0] = (f32x4){0.f, 0.f, 0.f, 0.f};
    po[1] = (f32x4){0.f, 0.f, 0.f, 0.f};
    const unsigned short* vrow = vbase + (size_t)(w * 16 + frow) * CMAX;
    for (int t = 0; t < NT; ++t) {
#pragma unroll
        for (int ks = 0; ks < 2; ++ks) {
            const int kb0 = (t << 6) + ks * 32 + fk;
            const short8 vf = *(const short8*)(vrow + kb0);
#pragma unroll
            for (int mi = 0; mi < 2; ++mi) {
                const short8 pf = *(const short8*)&scb[mi * 16 + frow][kb0];
                po[mi] = __builtin_amdgcn_mfma_f32_16x16x32_bf16(pf, vf, po[mi], 0, 0, 0);
            }
        }
    }

#pragma unroll
    for (int mi = 0; mi < 2; ++mi)
#pragma unroll
        for (int r = 0; r < 4; ++r) {
            const int row = mi * 16 + (lane >> 4) * 4 + r;
            const int m = g0 + row;
            if (m < NROWS) {
                const float inv = 1.0f / (rsw[0][row] + rsw[1][row]
                                        + rsw[2][row] + rsw[3][row]);
                outb[((size_t)b * NROWS + m) * DDIM
                     + h * HD + w * 16 + frow] = f2bf(po[mi][r] * inv);
            }
        }
}

// ---------------------------------------------------------------------------
extern "C" void kernel_launch(void* const* d_in, const int* in_sizes, int n_in,
                              void* d_out, int out_size, void* d_ws, size_t ws_size,
                              hipStream_t stream)
{
    const float* item = (const float*)d_in[0];
    const float* user = (const float*)d_in[1];
    const int*   resp = (const int*)d_in[2];
    const float* Wq = (const float*)d_in[3];  const float* bq = (const float*)d_in[4];
    const float* Wk = (const float*)d_in[5];  const float* bk = (const float*)d_in[6];
    const float* Wv = (const float*)d_in[7];  const float* bv = (const float*)d_in[8];
    const float* Wo = (const float*)d_in[9];  const float* bo = (const float*)d_in[10];
    const float* lng = (const float*)d_in[11]; const float* lnb = (const float*)d_in[12];
    const float* W1 = (const float*)d_in[13]; const float* b1 = (const float*)d_in[14];
    const float* W2 = (const float*)d_in[15]; const float* b2 = (const float*)d_in[16];
    float* out = (float*)d_out;

    char* p = (char*)d_ws;
    auto alloc = [&](size_t bytes) { char* r = p; p += (bytes + 255) & ~(size_t)255; return r; };
    const size_t NITEM = (size_t)BATCH * NROWS * EDIM;
    const size_t NW    = (size_t)DDIM * DDIM;
    const size_t NQ    = (size_t)BATCH * HEADS * LFULL * HD;
    const size_t NC    = (size_t)BATCH * HEADS * CMAX * HD;
    const size_t NMD   = (size_t)MTOT * DDIM;
    const size_t PAD   = 8192;

    unsigned short* itemb  = (unsigned short*)alloc(NITEM * 2);
    unsigned short* Wqkvb  = (unsigned short*)alloc((size_t)NQKV * EDIM * 2);
    unsigned short* Wob    = (unsigned short*)alloc(NW * 2);
    unsigned short* W1gb   = (unsigned short*)alloc(NW * 2);
    unsigned short* qb     = (unsigned short*)alloc(NQ * 2 + PAD);
    unsigned short* kcb    = (unsigned short*)alloc(NC * 2 + PAD);
    unsigned short* vcb    = (unsigned short*)alloc(NC * 2 + PAD);
    unsigned short* aob    = (unsigned short*)alloc(NMD * 2);
    unsigned short* fb16   = (unsigned short*)alloc(NMD * 2);
    float*  uball  = (float*)alloc((size_t)BATCH * NQKV * 4);
    float*  part   = (float*)alloc((size_t)MTOT * 8 * 4);
    float*  rowpart= (float*)alloc((size_t)MTOT * 16 * 4);
    float2* c1c2   = (float2*)alloc((size_t)DDIM * 8);
    int* cidx    = (int*)alloc((size_t)BATCH * 512 * 4);
    int* cnt     = (int*)alloc((size_t)BATCH * 32 * 4);

    PrepArgs pa;
    pa.item = item;
    pa.Wq = Wq; pa.Wk = Wk; pa.Wv = Wv; pa.Wo = Wo; pa.W1 = W1;
    pa.lng = lng; pa.lnb = lnb;
    pa.itemb = itemb; pa.Wqkvb = Wqkvb; pa.Wob = Wob;
    pa.W1gb = W1gb; pa.c1c2 = c1c2;
    prep_light<<<dim3(PREP_TOTAL), 256, 0, stream>>>(pa);

    compact_kernel<<<dim3(BATCH), 64, 0, stream>>>(resp, cidx, cnt);

    user_bias_kernel<<<dim3(BATCH, 3), 256, 0, stream>>>(
        user, Wq, bq, Wk, bk, Wv, bv, uball, qb, kcb, vcb);

    gemm_qkv<<<dim3(NQKV / 128, MTOT / 128), 256, 0, stream>>>(
        itemb, Wqkvb, uball, cidx, qb, kcb, vcb);

    attn_mfma<<<dim3(NRB, HEADS, BATCH), 256, 0, stream>>>(qb, kcb, vcb, cnt, aob);

    dim3 gg(DDIM / 128, MTOT / 128);
    gemm_bf16<1><<<gg, 256, 0, stream>>>(aob, Wob, bo, fb16, nullptr, rowpart,
                                         nullptr, nullptr);
    gemm_bf16<2><<<gg, 256, 0, stream>>>(fb16, W1gb, b1, nullptr, W2, part,
                                         rowpart, c1c2);
    w2red_kernel<<<dim3((MTOT + 255) / 256), 256, 0, stream>>>(part, b2, out);
}

// Round 16
// 243.646 us; speedup vs baseline: 1.2622x; 1.2622x over previous
//
#include <hip/hip_runtime.h>
#include <math.h>

#define BATCH 64
#define SLATES 25
#define KPS 20
#define EDIM 256
#define DDIM 512
#define HEADS 8
#define HD 64
#define LFULL 501
#define NROWS 500
#define MTOT (BATCH*NROWS)   // 32000
#define CMAX 512
#define NQKV 1536
#define RB 32
#define NRB ((NROWS + RB - 1) / RB)   // 16

// prep_light block ranges (uniform light blocks only)
#define NCVT  8000
#define NPACK 384
#define NWO   256
#define NW1P  128
#define PREP_TOTAL (NCVT + NPACK + NWO + NW1P)   // 8768

typedef __attribute__((ext_vector_type(8))) short short8;
typedef __attribute__((ext_vector_type(4))) float f32x4;

__device__ __forceinline__ unsigned short f2bf(float x) {
    unsigned int u = __builtin_bit_cast(unsigned int, x);
    u = (u + 0x7FFFu + ((u >> 16) & 1u)) >> 16;
    return (unsigned short)u;
}
__device__ __forceinline__ float bf2f(unsigned short s) {
    unsigned int u = ((unsigned int)s) << 16;
    return __builtin_bit_cast(float, u);
}
__device__ __forceinline__ float gelu_exact(float x) {
    return 0.5f * x * (1.0f + erff(x * 0.70710678118654752440f));
}
__device__ __forceinline__ void gload16(const void* g, void* l) {
    __builtin_amdgcn_global_load_lds(
        (const __attribute__((address_space(1))) void*)g,
        (__attribute__((address_space(3))) void*)l, 16, 0, 0);
}

// ---------------------------------------------------------------------------
// Fused light prep: item cvt / Wqkv pack / Wo cvt / W1g prep.
// ---------------------------------------------------------------------------
struct PrepArgs {
    const float* item;
    const float* Wq; const float* Wk; const float* Wv;
    const float* Wo; const float* W1;
    const float* lng; const float* lnb;
    unsigned short* itemb; unsigned short* Wqkvb; unsigned short* Wob;
    unsigned short* W1gb; float2* c1c2;
};

__global__ __launch_bounds__(256) void prep_light(PrepArgs a)
{
    const int bid = blockIdx.x;
    const int tid = threadIdx.x;

    if (bid < NCVT) {
        const int i = bid * 256 + tid;
        float4 v = ((const float4*)a.item)[i];
        ushort4 o;
        o.x = f2bf(v.x); o.y = f2bf(v.y); o.z = f2bf(v.z); o.w = f2bf(v.w);
        ((ushort4*)a.itemb)[i] = o;
        return;
    }
    if (bid < NCVT + NPACK) {
        const int idx = bid - NCVT;
        const int y = idx / 128;
        const float* W = (y == 0) ? a.Wq : (y == 1) ? a.Wk : a.Wv;
        const int i = (idx % 128) * 256 + tid;
        const int row = i >> 6, c4 = (i & 63) * 4;
        float4 v = *(const float4*)&W[(size_t)row * DDIM + c4];
        ushort4 o;
        o.x = f2bf(v.x); o.y = f2bf(v.y); o.z = f2bf(v.z); o.w = f2bf(v.w);
        *(ushort4*)&a.Wqkvb[((size_t)y * DDIM + row) * EDIM + c4] = o;
        return;
    }
    if (bid < NCVT + NPACK + NWO) {
        const int i = (bid - NCVT - NPACK) * 256 + tid;
        float4 v = ((const float4*)a.Wo)[i];
        ushort4 o;
        o.x = f2bf(v.x); o.y = f2bf(v.y); o.z = f2bf(v.z); o.w = f2bf(v.w);
        ((ushort4*)a.Wob)[i] = o;
        return;
    }
    {
        const int row = (bid - NCVT - NPACK - NWO) * 4 + (tid >> 6);
        const int lane = tid & 63;
        float c1 = 0.f, c2 = 0.f;
#pragma unroll
        for (int i = 0; i < 8; ++i) {
            const int k = lane + i * 64;
            const float w = a.W1[(size_t)row * DDIM + k];
            const float gv = a.lng[k];
            c1 += w * a.lnb[k];
            c2 += w * gv;
            a.W1gb[(size_t)row * DDIM + k] = f2bf(w * gv);
        }
#pragma unroll
        for (int off = 32; off; off >>= 1) {
            c1 += __shfl_xor(c1, off, 64);
            c2 += __shfl_xor(c2, off, 64);
        }
        if (lane == 0) a.c1c2[row] = make_float2(c1, c2);
    }
}

// ---------------------------------------------------------------------------
// Click compaction: one wave per batch.
// ---------------------------------------------------------------------------
__global__ __launch_bounds__(64) void compact_kernel(
    const int* __restrict__ resp, int* __restrict__ cidx, int* __restrict__ cnt)
{
    const int b = blockIdx.x, lane = threadIdx.x;
    int a[8]; int c = 0;
#pragma unroll
    for (int j = 0; j < 8; ++j) {
        const int l = lane * 8 + j;
        int al = 0;
        if (l == 0) al = 1;
        else if (l <= NROWS) al = (resp[(size_t)b * NROWS + l - 1] > 0) ? 1 : 0;
        a[j] = al; c += al;
    }
    int incl = c;
#pragma unroll
    for (int off = 1; off < 64; off <<= 1) {
        int t = __shfl_up(incl, off, 64);
        if (lane >= off) incl += t;
    }
    int run = incl - c;
#pragma unroll
    for (int j = 0; j < 8; ++j) {
        const int l = lane * 8 + j;
        if (l >= 1 && l <= 481 && (l % 20) == 1)
            cnt[b * 32 + (l - 1) / 20] = run;
        cidx[b * 512 + l] = a[j] ? run : -1;
        run += a[j];
    }
}

// ---------------------------------------------------------------------------
// User bias: per-thread-output (full TLP) with float4 vectorized reads.
// grid (BATCH, 3), 256 threads; each thread computes 2 outputs.
// ---------------------------------------------------------------------------
__global__ __launch_bounds__(256) void user_bias_kernel(
    const float* __restrict__ user,
    const float* __restrict__ Wq, const float* __restrict__ bq,
    const float* __restrict__ Wk, const float* __restrict__ bk,
    const float* __restrict__ Wv, const float* __restrict__ bv,
    float* __restrict__ uball,
    unsigned short* __restrict__ qb, unsigned short* __restrict__ kc,
    unsigned short* __restrict__ vc)
{
    const int b = blockIdx.x, y = blockIdx.y;
    const int tid = threadIdx.x;
    const float* W  = (y == 0) ? Wq : (y == 1) ? Wk : Wv;
    const float* bi = (y == 0) ? bq : (y == 1) ? bk : bv;

    __shared__ __align__(16) float us[EDIM];
    if (tid < EDIM) us[tid] = user[b * EDIM + tid];
    __syncthreads();
    const float4* us4 = (const float4*)us;

#pragma unroll
    for (int half = 0; half < 2; ++half) {
        const int o = half * 256 + tid;
        const float4* wr4 = (const float4*)&W[(size_t)o * DDIM + EDIM];
        float s = bi[o];
#pragma unroll 8
        for (int e4 = 0; e4 < EDIM / 4; ++e4) {
            const float4 w = wr4[e4];
            const float4 u = us4[e4];
            s += u.x * w.x + u.y * w.y + u.z * w.z + u.w * w.w;
        }
        uball[(size_t)b * NQKV + y * DDIM + o] = s;
        const int hh = o >> 6, dd = o & 63;
        const size_t bh = (size_t)b * HEADS + hh;
        if (y == 0)      qb[(bh * LFULL) * HD + dd] = f2bf(bi[o]);
        else if (y == 1) kc[(bh * CMAX) * HD + dd] = f2bf(bi[o]);
        else             vc[(bh * HD + dd) * CMAX] = f2bf(bi[o]);
    }
}

// ---------------------------------------------------------------------------
// Merged QKV GEMM: counted-vmcnt 3-buffer pipeline + LDS-bounce coalesced
// epilogue + XCD-chunked block swizzle. Grid = (12, 250) = 3000 blocks.
// ---------------------------------------------------------------------------
__global__ __launch_bounds__(256) void gemm_qkv(
    const unsigned short* __restrict__ A,
    const unsigned short* __restrict__ Wqkv,
    const float* __restrict__ uball, const int* __restrict__ cidx,
    unsigned short* __restrict__ oq, unsigned short* __restrict__ ok,
    unsigned short* __restrict__ ov)
{
    const int tid = threadIdx.x;
    const int lin = blockIdx.y * gridDim.x + blockIdx.x;
    const int vb  = (lin & 7) * 375 + (lin >> 3);
    const int n0 = (vb % 12) * 128;   // 0..1535
    const int m0 = (vb / 12) * 128;
    const int lane = tid & 63, wid = tid >> 6;
    const int wm = (wid & 1) * 64, wn = (wid >> 1) * 64;

    __shared__ __align__(16) unsigned short sm[24576];
    __shared__ int cids[128];
    auto As = [&](int buf) { return (unsigned short(*)[32])(sm + buf * 4096); };
    auto Ws = [&](int buf) { return (unsigned short(*)[32])(sm + 12288 + buf * 4096); };
    auto bounce = (unsigned short(*)[136])sm;

    f32x4 acc[4][4];
#pragma unroll
    for (int i = 0; i < 4; ++i)
#pragma unroll
        for (int j = 0; j < 4; ++j) acc[i][j] = (f32x4){0.f, 0.f, 0.f, 0.f};

    const unsigned short* gA0 = &A[(size_t)(m0 + wid * 16 + (lane >> 2)) * EDIM + (lane & 3) * 8];
    const unsigned short* gA1 = gA0 + (size_t)64 * EDIM;
    const unsigned short* gW0 = &Wqkv[(size_t)(n0 + wid * 16 + (lane >> 2)) * EDIM + (lane & 3) * 8];
    const unsigned short* gW1 = gW0 + (size_t)64 * EDIM;
    const int frow = lane & 15, fk = (lane >> 4) * 8;

    auto stage = [&](int buf, int k0) {
        gload16(gA0 + k0, &As(buf)[wid * 16][0]);
        gload16(gA1 + k0, &As(buf)[64 + wid * 16][0]);
        gload16(gW0 + k0, &Ws(buf)[wid * 16][0]);
        gload16(gW1 + k0, &Ws(buf)[64 + wid * 16][0]);
    };
    stage(0, 0);
    stage(1, 32);

    const int nst = EDIM / 32;   // 8
    for (int t = 0; t < nst; ++t) {
        const int cur = t % 3;
        if (t < nst - 1) asm volatile("s_waitcnt vmcnt(4)" ::: "memory");
        else             asm volatile("s_waitcnt vmcnt(0)" ::: "memory");
        __builtin_amdgcn_s_barrier();
        __builtin_amdgcn_sched_barrier(0);
        short8 af[4], wf[4];
#pragma unroll
        for (int mi = 0; mi < 4; ++mi)
            af[mi] = *(const short8*)&As(cur)[wm + mi * 16 + frow][fk];
#pragma unroll
        for (int ni = 0; ni < 4; ++ni)
            wf[ni] = *(const short8*)&Ws(cur)[wn + ni * 16 + frow][fk];
#pragma unroll
        for (int mi = 0; mi < 4; ++mi)
#pragma unroll
            for (int ni = 0; ni < 4; ++ni)
                acc[mi][ni] = __builtin_amdgcn_mfma_f32_16x16x32_bf16(
                    af[mi], wf[ni], acc[mi][ni], 0, 0, 0);
        if (t + 2 < nst) stage((t + 2) % 3, (t + 2) * 32);
    }

    // ---- epilogue: bounce through LDS for coalesced stores ----
    const int z = n0 >> 9;               // 0=q 1=k 2=v
    const int b0 = m0 / NROWS;
    const int split = (b0 + 1) * NROWS;
    const int b1 = (split <= m0 + 127) ? b0 + 1 : b0;
    float ub0[4], ub1[4];
#pragma unroll
    for (int ni = 0; ni < 4; ++ni) {
        const int np = n0 + wn + ni * 16 + frow;
        ub0[ni] = uball[(size_t)b0 * NQKV + np];
        ub1[ni] = uball[(size_t)b1 * NQKV + np];
    }
    __syncthreads();
    if (z != 0 && tid < 128) {
        const int m = m0 + tid;
        const int b = (m >= split) ? b1 : b0;
        cids[tid] = cidx[b * 512 + (m - b * NROWS + 1)];
    }
#pragma unroll
    for (int mi = 0; mi < 4; ++mi)
#pragma unroll
        for (int r = 0; r < 4; ++r) {
            const int ml = wm + mi * 16 + (lane >> 4) * 4 + r;
            const bool hi = (m0 + ml >= split);
#pragma unroll
            for (int ni = 0; ni < 4; ++ni)
                bounce[ml][wn + ni * 16 + frow] =
                    f2bf(acc[mi][ni][r] + (hi ? ub1[ni] : ub0[ni]));
        }
    __syncthreads();

    const int h0 = (n0 & 511) >> 6;
    if (z == 0) {
        const int row = tid >> 1, half = tid & 1;
        const int m = m0 + row;
        const int b = (m >= split) ? b1 : b0;
        const int l = m - b * NROWS + 1;
        unsigned short* dst = &oq[(((size_t)b * HEADS + h0 + half) * LFULL + l) * HD];
        const unsigned short* src = &bounce[row][half * 64];
#pragma unroll
        for (int j = 0; j < 8; ++j)
            *(uint4*)(dst + j * 8) = *(const uint4*)(src + j * 8);
    } else if (z == 1) {
        const int row = tid >> 1, half = tid & 1;
        const int c = cids[row];
        if (c >= 0) {
            const int m = m0 + row;
            const int b = (m >= split) ? b1 : b0;
            unsigned short* dst = &ok[(((size_t)b * HEADS + h0 + half) * CMAX + c) * HD];
            const unsigned short* src = &bounce[row][half * 64];
#pragma unroll
            for (int j = 0; j < 8; ++j)
                *(uint4*)(dst + j * 8) = *(const uint4*)(src + j * 8);
        }
    } else {
        const int col = tid & 127, mh = tid >> 7;
        const int hh = h0 + (col >> 6), dd = col & 63;
        for (int mm = 0; mm < 64; ++mm) {
            const int row = mh * 64 + mm;
            const int c = cids[row];
            if (c >= 0) {
                const int m = m0 + row;
                const int b = (m >= split) ? b1 : b0;
                ov[((size_t)b * HEADS + hh) * (size_t)(HD * CMAX)
                   + (size_t)dd * CMAX + c] = bounce[row][col];
            }
        }
    }
}

// ---------------------------------------------------------------------------
// Generic bf16 GEMM (counted-vmcnt 3-buffer) + XCD swizzle (1000 = 8 x 125).
// MODE 1 (Wo): +bias, bf16 out, per-row partial (sum f, sum f^2) -> rowpart.
// MODE 2 (W1g): inline LN stats from rowpart, LN-folded gelu + W2 dot.
// ---------------------------------------------------------------------------
template <int MODE>
__global__ __launch_bounds__(256) void gemm_bf16(
    const unsigned short* __restrict__ A,
    const unsigned short* __restrict__ W,
    const float* __restrict__ bias, void* __restrict__ outp,
    const float* __restrict__ W2, float* __restrict__ part,
    const float* __restrict__ rowpart, const float2* __restrict__ c1c2)
{
    const int tid = threadIdx.x;
    const int lin = blockIdx.y * gridDim.x + blockIdx.x;
    const int vb  = (lin & 7) * 125 + (lin >> 3);
    const int n0 = (vb % 4) * 128;
    const int m0 = (vb / 4) * 128;
    const int lane = tid & 63, wid = tid >> 6;
    const int wm = (wid & 1) * 64, wn = (wid >> 1) * 64;

    __shared__ unsigned short As[3][128][32];
    __shared__ unsigned short Ws[3][128][32];
    __shared__ float2 smusr[128];

    f32x4 acc[4][4];
#pragma unroll
    for (int i = 0; i < 4; ++i)
#pragma unroll
        for (int j = 0; j < 4; ++j) acc[i][j] = (f32x4){0.f, 0.f, 0.f, 0.f};

    const unsigned short* gA0 = &A[(size_t)(m0 + wid * 16 + (lane >> 2)) * DDIM + (lane & 3) * 8];
    const unsigned short* gA1 = gA0 + (size_t)64 * DDIM;
    const unsigned short* gW0 = &W[(size_t)(n0 + wid * 16 + (lane >> 2)) * DDIM + (lane & 3) * 8];
    const unsigned short* gW1 = gW0 + (size_t)64 * DDIM;
    const int frow = lane & 15, fk = (lane >> 4) * 8;

    auto stage = [&](int buf, int k0) {
        gload16(gA0 + k0, &As[buf][wid * 16][0]);
        gload16(gA1 + k0, &As[buf][64 + wid * 16][0]);
        gload16(gW0 + k0, &Ws[buf][wid * 16][0]);
        gload16(gW1 + k0, &Ws[buf][64 + wid * 16][0]);
    };
    stage(0, 0);
    stage(1, 32);

    const int nst = DDIM / 32;   // 16
    for (int t = 0; t < nst; ++t) {
        const int cur = t % 3;
        if (t < nst - 1) asm volatile("s_waitcnt vmcnt(4)" ::: "memory");
        else             asm volatile("s_waitcnt vmcnt(0)" ::: "memory");
        __builtin_amdgcn_s_barrier();
        __builtin_amdgcn_sched_barrier(0);
        short8 af[4], wf[4];
#pragma unroll
        for (int mi = 0; mi < 4; ++mi)
            af[mi] = *(const short8*)&As[cur][wm + mi * 16 + frow][fk];
#pragma unroll
        for (int ni = 0; ni < 4; ++ni)
            wf[ni] = *(const short8*)&Ws[cur][wn + ni * 16 + frow][fk];
#pragma unroll
        for (int mi = 0; mi < 4; ++mi)
#pragma unroll
            for (int ni = 0; ni < 4; ++ni)
                acc[mi][ni] = __builtin_amdgcn_mfma_f32_16x16x32_bf16(
                    af[mi], wf[ni], acc[mi][ni], 0, 0, 0);
        if (t + 2 < nst) stage((t + 2) % 3, (t + 2) * 32);
    }

    const int slot = (n0 >> 7) * 2 + (wn >> 6);   // 0..7
    if (MODE == 1) {
        float bv4[4];
#pragma unroll
        for (int ni = 0; ni < 4; ++ni) bv4[ni] = bias[n0 + wn + ni * 16 + frow];
#pragma unroll
        for (int mi = 0; mi < 4; ++mi)
#pragma unroll
            for (int r = 0; r < 4; ++r) {
                const int m = m0 + wm + mi * 16 + (lane >> 4) * 4 + r;
                float s1 = 0.f, s2 = 0.f;
#pragma unroll
                for (int ni = 0; ni < 4; ++ni) {
                    const float v = acc[mi][ni][r] + bv4[ni];
                    s1 += v; s2 += v * v;
                    ((unsigned short*)outp)[(size_t)m * DDIM + n0 + wn + ni * 16 + frow]
                        = f2bf(v);
                }
                s1 += __shfl_xor(s1, 1, 64); s2 += __shfl_xor(s2, 1, 64);
                s1 += __shfl_xor(s1, 2, 64); s2 += __shfl_xor(s2, 2, 64);
                s1 += __shfl_xor(s1, 4, 64); s2 += __shfl_xor(s2, 4, 64);
                s1 += __shfl_xor(s1, 8, 64); s2 += __shfl_xor(s2, 8, 64);
                if (frow == 0) {
                    part[((size_t)m << 4) + slot * 2]     = s1;
                    part[((size_t)m << 4) + slot * 2 + 1] = s2;
                }
            }
    } else {
        if (tid < 128) {
            const float* pp = rowpart + ((size_t)(m0 + tid) << 4);
            float s1 = 0.f, s2 = 0.f;
#pragma unroll
            for (int i = 0; i < 8; ++i) { s1 += pp[i * 2]; s2 += pp[i * 2 + 1]; }
            const float mu = s1 * (1.0f / DDIM);
            const float var = s2 * (1.0f / DDIM) - mu * mu;
            smusr[tid] = make_float2(mu, rsqrtf(var + 1e-5f));
        }
        float w2v[4], cb[4], c2v[4];
#pragma unroll
        for (int ni = 0; ni < 4; ++ni) {
            const int n = n0 + wn + ni * 16 + frow;
            w2v[ni] = W2[n];
            const float2 cc = c1c2[n];
            cb[ni]  = cc.x + bias[n];
            c2v[ni] = cc.y;
        }
        __syncthreads();
#pragma unroll
        for (int mi = 0; mi < 4; ++mi)
#pragma unroll
            for (int r = 0; r < 4; ++r) {
                const int ml = wm + mi * 16 + (lane >> 4) * 4 + r;
                const float2 ms = smusr[ml];
                float s = 0.f;
#pragma unroll
                for (int ni = 0; ni < 4; ++ni)
                    s += gelu_exact(ms.y * (acc[mi][ni][r] - ms.x * c2v[ni]) + cb[ni])
                         * w2v[ni];
                s += __shfl_xor(s, 1, 64);
                s += __shfl_xor(s, 2, 64);
                s += __shfl_xor(s, 4, 64);
                s += __shfl_xor(s, 8, 64);
                if (frow == 0)
                    part[(size_t)(m0 + ml) * 8 + slot] = s;
            }
    }
}

// ---------------------------------------------------------------------------
// Final reduction: out[m] = b2 + sum of 8 partials.
// ---------------------------------------------------------------------------
__global__ __launch_bounds__(256) void w2red_kernel(
    const float* __restrict__ part, const float* __restrict__ b2,
    float* __restrict__ out)
{
    const int m = blockIdx.x * 256 + threadIdx.x;
    if (m >= MTOT) return;
    const float* p = part + (size_t)m * 8;
    float s = b2[0];
#pragma unroll
    for (int i = 0; i < 8; ++i) s += p[i];
    out[m] = s;
}

// ---------------------------------------------------------------------------
// Attention v7: row-packed 32-row blocks, per-row key-count mask, fused exp,
// XCD-chunked swizzle (8192 = 8 x 1024).
// ---------------------------------------------------------------------------
__global__ __launch_bounds__(256) void attn_mfma(
    const unsigned short* __restrict__ qx, const unsigned short* __restrict__ kc,
    const unsigned short* __restrict__ vc, const int* __restrict__ cnt,
    unsigned short* __restrict__ outb)
{
    const int lin = blockIdx.x + NRB * (blockIdx.y + HEADS * blockIdx.z);
    const int vbk = (lin & 7) * (NRB * HEADS * BATCH / 8) + (lin >> 3);
    const int rbk = vbk % NRB;
    const int h   = (vbk / NRB) % HEADS;
    const int b   = vbk / (NRB * HEADS);
    const int g0  = rbk * RB;

    const int tid = threadIdx.x, lane = tid & 63, w = tid >> 6;

    __shared__ __align__(16) unsigned short scb[RB][520];
    __shared__ float rsw[4][RB];
    __shared__ int snck[RB];

    const int frow = lane & 15, fk = (lane >> 4) * 8;
    const size_t bh = (size_t)b * HEADS + h;
    const unsigned short* kbase = kc + bh * (CMAX * HD);
    const unsigned short* vbase = vc + bh * (HD * CMAX);

    if (tid < RB) {
        const int s = (g0 + tid >= NROWS ? NROWS - 1 : g0 + tid) / KPS;
        snck[tid] = cnt[b * 32 + s];
    }

    short8 qf[2][2];
#pragma unroll
    for (int mi = 0; mi < 2; ++mi) {
        const int qrow = g0 + mi * 16 + frow;
#pragma unroll
        for (int ks = 0; ks < 2; ++ks) {
            short8 v = {};
            if (qrow < NROWS)
                v = *(const short8*)&qx[(bh * LFULL + qrow + 1) * HD + ks * 32 + fk];
            qf[mi][ks] = v;
        }
    }
    __syncthreads();

    int nck8[2][4];
#pragma unroll
    for (int mi = 0; mi < 2; ++mi)
#pragma unroll
        for (int r = 0; r < 4; ++r)
            nck8[mi][r] = snck[mi * 16 + (lane >> 4) * 4 + r];
    const int nmax = snck[RB - 1];
    const int NT = (nmax + 63) >> 6;

    f32x4 rsum[2];
    rsum[0] = (f32x4){0.f, 0.f, 0.f, 0.f};
    rsum[1] = (f32x4){0.f, 0.f, 0.f, 0.f};
    for (int t = 0; t < NT; ++t) {
        const int key = (t << 6) + w * 16 + frow;
        const unsigned short* kr = kbase + (size_t)key * HD;
        const short8 kf0 = *(const short8*)(kr + fk);
        const short8 kf1 = *(const short8*)(kr + 32 + fk);
        f32x4 s2[2];
#pragma unroll
        for (int mi = 0; mi < 2; ++mi) {
            s2[mi] = (f32x4){0.f, 0.f, 0.f, 0.f};
            s2[mi] = __builtin_amdgcn_mfma_f32_16x16x32_bf16(qf[mi][0], kf0, s2[mi], 0, 0, 0);
            s2[mi] = __builtin_amdgcn_mfma_f32_16x16x32_bf16(qf[mi][1], kf1, s2[mi], 0, 0, 0);
        }
#pragma unroll
        for (int mi = 0; mi < 2; ++mi)
#pragma unroll
            for (int r = 0; r < 4; ++r) {
                const int row = mi * 16 + (lane >> 4) * 4 + r;
                const float p = (key < nck8[mi][r]) ? __expf(s2[mi][r] * 0.125f) : 0.f;
                rsum[mi][r] += p;
                scb[row][key] = f2bf(p);
            }
    }
#pragma unroll
    for (int mi = 0; mi < 2; ++mi)
#pragma unroll
        for (int r = 0; r < 4; ++r) {
            float v = rsum[mi][r];
            v += __shfl_xor(v, 1, 64);
            v += __shfl_xor(v, 2, 64);
            v += __shfl_xor(v, 4, 64);
            v += __shfl_xor(v, 8, 64);
            if (frow == 0)
                rsw[w][mi * 16 + (lane >> 4) * 4 + r] = v;
        }
    __syncthreads();

    f32x4 po[2];
    po[0] = (f32x4){0.f, 0.f, 0.f, 0.f};
    po[1] = (f32x4){0.f, 0.f, 0.f, 0.f};
    const unsigned short* vrow = vbase + (size_t)(w * 16 + frow) * CMAX;
    for (int t = 0; t < NT; ++t) {
#pragma unroll
        for (int ks = 0; ks < 2; ++ks) {
            const int kb0 = (t << 6) + ks * 32 + fk;
            const short8 vf = *(const short8*)(vrow + kb0);
#pragma unroll
            for (int mi = 0; mi < 2; ++mi) {
                const short8 pf = *(const short8*)&scb[mi * 16 + frow][kb0];
                po[mi] = __builtin_amdgcn_mfma_f32_16x16x32_bf16(pf, vf, po[mi], 0, 0, 0);
            }
        }
    }

#pragma unroll
    for (int mi = 0; mi < 2; ++mi)
#pragma unroll
        for (int r = 0; r < 4; ++r) {
            const int row = mi * 16 + (lane >> 4) * 4 + r;
            const int m = g0 + row;
            if (m < NROWS) {
                const float inv = 1.0f / (rsw[0][row] + rsw[1][row]
                                        + rsw[2][row] + rsw[3][row]);
                outb[((size_t)b * NROWS + m) * DDIM
                     + h * HD + w * 16 + frow] = f2bf(po[mi][r] * inv);
            }
        }
}

// ---------------------------------------------------------------------------
extern "C" void kernel_launch(void* const* d_in, const int* in_sizes, int n_in,
                              void* d_out, int out_size, void* d_ws, size_t ws_size,
                              hipStream_t stream)
{
    const float* item = (const float*)d_in[0];
    const float* user = (const float*)d_in[1];
    const int*   resp = (const int*)d_in[2];
    const float* Wq = (const float*)d_in[3];  const float* bq = (const float*)d_in[4];
    const float* Wk = (const float*)d_in[5];  const float* bk = (const float*)d_in[6];
    const float* Wv = (const float*)d_in[7];  const float* bv = (const float*)d_in[8];
    const float* Wo = (const float*)d_in[9];  const float* bo = (const float*)d_in[10];
    const float* lng = (const float*)d_in[11]; const float* lnb = (const float*)d_in[12];
    const float* W1 = (const float*)d_in[13]; const float* b1 = (const float*)d_in[14];
    const float* W2 = (const float*)d_in[15]; const float* b2 = (const float*)d_in[16];
    float* out = (float*)d_out;

    char* p = (char*)d_ws;
    auto alloc = [&](size_t bytes) { char* r = p; p += (bytes + 255) & ~(size_t)255; return r; };
    const size_t NITEM = (size_t)BATCH * NROWS * EDIM;
    const size_t NW    = (size_t)DDIM * DDIM;
    const size_t NQ    = (size_t)BATCH * HEADS * LFULL * HD;
    const size_t NC    = (size_t)BATCH * HEADS * CMAX * HD;
    const size_t NMD   = (size_t)MTOT * DDIM;
    const size_t PAD   = 8192;

    unsigned short* itemb  = (unsigned short*)alloc(NITEM * 2);
    unsigned short* Wqkvb  = (unsigned short*)alloc((size_t)NQKV * EDIM * 2);
    unsigned short* Wob    = (unsigned short*)alloc(NW * 2);
    unsigned short* W1gb   = (unsigned short*)alloc(NW * 2);
    unsigned short* qb     = (unsigned short*)alloc(NQ * 2 + PAD);
    unsigned short* kcb    = (unsigned short*)alloc(NC * 2 + PAD);
    unsigned short* vcb    = (unsigned short*)alloc(NC * 2 + PAD);
    unsigned short* aob    = (unsigned short*)alloc(NMD * 2);
    unsigned short* fb16   = (unsigned short*)alloc(NMD * 2);
    float*  uball  = (float*)alloc((size_t)BATCH * NQKV * 4);
    float*  part   = (float*)alloc((size_t)MTOT * 8 * 4);
    float*  rowpart= (float*)alloc((size_t)MTOT * 16 * 4);
    float2* c1c2   = (float2*)alloc((size_t)DDIM * 8);
    int* cidx    = (int*)alloc((size_t)BATCH * 512 * 4);
    int* cnt     = (int*)alloc((size_t)BATCH * 32 * 4);

    PrepArgs pa;
    pa.item = item;
    pa.Wq = Wq; pa.Wk = Wk; pa.Wv = Wv; pa.Wo = Wo; pa.W1 = W1;
    pa.lng = lng; pa.lnb = lnb;
    pa.itemb = itemb; pa.Wqkvb = Wqkvb; pa.Wob = Wob;
    pa.W1gb = W1gb; pa.c1c2 = c1c2;
    prep_light<<<dim3(PREP_TOTAL), 256, 0, stream>>>(pa);

    compact_kernel<<<dim3(BATCH), 64, 0, stream>>>(resp, cidx, cnt);

    user_bias_kernel<<<dim3(BATCH, 3), 256, 0, stream>>>(
        user, Wq, bq, Wk, bk, Wv, bv, uball, qb, kcb, vcb);

    gemm_qkv<<<dim3(NQKV / 128, MTOT / 128), 256, 0, stream>>>(
        itemb, Wqkvb, uball, cidx, qb, kcb, vcb);

    attn_mfma<<<dim3(NRB, HEADS, BATCH), 256, 0, stream>>>(qb, kcb, vcb, cnt, aob);

    dim3 gg(DDIM / 128, MTOT / 128);
    gemm_bf16<1><<<gg, 256, 0, stream>>>(aob, Wob, bo, fb16, nullptr, rowpart,
                                         nullptr, nullptr);
    gemm_bf16<2><<<gg, 256, 0, stream>>>(fb16, W1gb, b1, nullptr, W2, part,
                                         rowpart, c1c2);
    w2red_kernel<<<dim3((MTOT + 255) / 256), 256, 0, stream>>>(part, b2, out);
}

// Round 17
// 242.571 us; speedup vs baseline: 1.2678x; 1.0044x over previous
//
#include <hip/hip_runtime.h>
#include <math.h>

#define BATCH 64
#define SLATES 25
#define KPS 20
#define EDIM 256
#define DDIM 512
#define HEADS 8
#define HD 64
#define LFULL 501
#define NROWS 500
#define MTOT (BATCH*NROWS)   // 32000
#define CMAX 512
#define NQKV 1536
#define RB 32
#define NRB ((NROWS + RB - 1) / RB)   // 16

// prep_all block ranges: HEAVY FIRST (user_bias), then compact, then light.
#define NUB   192
#define NCOMP 64
#define NCVT  8000
#define NPACK 384
#define NWO   256
#define NW1P  128
#define OFF_COMP (NUB)                     // 192
#define OFF_CVT  (OFF_COMP + NCOMP)        // 256
#define OFF_PACK (OFF_CVT + NCVT)          // 8256
#define OFF_WO   (OFF_PACK + NPACK)        // 8640
#define OFF_W1P  (OFF_WO + NWO)            // 8896
#define PREP_TOTAL (OFF_W1P + NW1P)        // 9024

typedef __attribute__((ext_vector_type(8))) short short8;
typedef __attribute__((ext_vector_type(4))) float f32x4;

__device__ __forceinline__ unsigned short f2bf(float x) {
    unsigned int u = __builtin_bit_cast(unsigned int, x);
    u = (u + 0x7FFFu + ((u >> 16) & 1u)) >> 16;
    return (unsigned short)u;
}
__device__ __forceinline__ float bf2f(unsigned short s) {
    unsigned int u = ((unsigned int)s) << 16;
    return __builtin_bit_cast(float, u);
}
__device__ __forceinline__ float gelu_exact(float x) {
    return 0.5f * x * (1.0f + erff(x * 0.70710678118654752440f));
}
__device__ __forceinline__ void gload16(const void* g, void* l) {
    __builtin_amdgcn_global_load_lds(
        (const __attribute__((address_space(1))) void*)g,
        (__attribute__((address_space(3))) void*)l, 16, 0, 0);
}

// ---------------------------------------------------------------------------
// Fused prep: user_bias (heavy, first) / compact / item cvt / Wqkv pack /
// Wo cvt / W1g prep. All branches block-uniform.
// ---------------------------------------------------------------------------
struct PrepArgs {
    const float* item; const float* user; const int* resp;
    const float* Wq; const float* bq;
    const float* Wk; const float* bk;
    const float* Wv; const float* bv;
    const float* Wo; const float* W1;
    const float* lng; const float* lnb;
    unsigned short* itemb; unsigned short* Wqkvb; unsigned short* Wob;
    unsigned short* W1gb; float2* c1c2;
    int* cidx; int* cnt; float* uball;
    unsigned short* qb; unsigned short* kc; unsigned short* vc;
};

__global__ __launch_bounds__(256) void prep_all(PrepArgs a)
{
    const int bid = blockIdx.x;
    const int tid = threadIdx.x;

    if (bid < NUB) {
        // user bias: per-thread-output, float4 reads (heavy -> dispatched first)
        const int b = bid % BATCH;
        const int y = bid / BATCH;
        const float* W  = (y == 0) ? a.Wq : (y == 1) ? a.Wk : a.Wv;
        const float* bi = (y == 0) ? a.bq : (y == 1) ? a.bk : a.bv;

        __shared__ __align__(16) float us[EDIM];
        if (tid < EDIM) us[tid] = a.user[b * EDIM + tid];
        __syncthreads();
        const float4* us4 = (const float4*)us;

#pragma unroll
        for (int half = 0; half < 2; ++half) {
            const int o = half * 256 + tid;
            const float4* wr4 = (const float4*)&W[(size_t)o * DDIM + EDIM];
            float s = bi[o];
#pragma unroll 8
            for (int e4 = 0; e4 < EDIM / 4; ++e4) {
                const float4 w = wr4[e4];
                const float4 u = us4[e4];
                s += u.x * w.x + u.y * w.y + u.z * w.z + u.w * w.w;
            }
            a.uball[(size_t)b * NQKV + y * DDIM + o] = s;
            const int hh = o >> 6, dd = o & 63;
            const size_t bh = (size_t)b * HEADS + hh;
            if (y == 0)      a.qb[(bh * LFULL) * HD + dd] = f2bf(bi[o]);
            else if (y == 1) a.kc[(bh * CMAX) * HD + dd] = f2bf(bi[o]);
            else             a.vc[(bh * HD + dd) * CMAX] = f2bf(bi[o]);
        }
        return;
    }
    if (bid < OFF_CVT) {
        // click compaction (wave 0 of the block)
        if (tid >= 64) return;
        const int b = bid - OFF_COMP;
        const int lane = tid;
        int av[8]; int c = 0;
#pragma unroll
        for (int j = 0; j < 8; ++j) {
            const int l = lane * 8 + j;
            int al = 0;
            if (l == 0) al = 1;
            else if (l <= NROWS) al = (a.resp[(size_t)b * NROWS + l - 1] > 0) ? 1 : 0;
            av[j] = al; c += al;
        }
        int incl = c;
#pragma unroll
        for (int off = 1; off < 64; off <<= 1) {
            int t = __shfl_up(incl, off, 64);
            if (lane >= off) incl += t;
        }
        int run = incl - c;
#pragma unroll
        for (int j = 0; j < 8; ++j) {
            const int l = lane * 8 + j;
            if (l >= 1 && l <= 481 && (l % 20) == 1)
                a.cnt[b * 32 + (l - 1) / 20] = run;
            a.cidx[b * 512 + l] = av[j] ? run : -1;
            run += av[j];
        }
        return;
    }
    if (bid < OFF_PACK) {
        const int i = (bid - OFF_CVT) * 256 + tid;
        float4 v = ((const float4*)a.item)[i];
        ushort4 o;
        o.x = f2bf(v.x); o.y = f2bf(v.y); o.z = f2bf(v.z); o.w = f2bf(v.w);
        ((ushort4*)a.itemb)[i] = o;
        return;
    }
    if (bid < OFF_WO) {
        const int idx = bid - OFF_PACK;
        const int y = idx / 128;
        const float* W = (y == 0) ? a.Wq : (y == 1) ? a.Wk : a.Wv;
        const int i = (idx % 128) * 256 + tid;
        const int row = i >> 6, c4 = (i & 63) * 4;
        float4 v = *(const float4*)&W[(size_t)row * DDIM + c4];
        ushort4 o;
        o.x = f2bf(v.x); o.y = f2bf(v.y); o.z = f2bf(v.z); o.w = f2bf(v.w);
        *(ushort4*)&a.Wqkvb[((size_t)y * DDIM + row) * EDIM + c4] = o;
        return;
    }
    if (bid < OFF_W1P) {
        const int i = (bid - OFF_WO) * 256 + tid;
        float4 v = ((const float4*)a.Wo)[i];
        ushort4 o;
        o.x = f2bf(v.x); o.y = f2bf(v.y); o.z = f2bf(v.z); o.w = f2bf(v.w);
        ((ushort4*)a.Wob)[i] = o;
        return;
    }
    {
        const int row = (bid - OFF_W1P) * 4 + (tid >> 6);
        const int lane = tid & 63;
        float c1 = 0.f, c2 = 0.f;
#pragma unroll
        for (int i = 0; i < 8; ++i) {
            const int k = lane + i * 64;
            const float w = a.W1[(size_t)row * DDIM + k];
            const float gv = a.lng[k];
            c1 += w * a.lnb[k];
            c2 += w * gv;
            a.W1gb[(size_t)row * DDIM + k] = f2bf(w * gv);
        }
#pragma unroll
        for (int off = 32; off; off >>= 1) {
            c1 += __shfl_xor(c1, off, 64);
            c2 += __shfl_xor(c2, off, 64);
        }
        if (lane == 0) a.c1c2[row] = make_float2(c1, c2);
    }
}

// ---------------------------------------------------------------------------
// Merged QKV GEMM: counted-vmcnt 3-buffer pipeline (stage issued right after
// barrier) + LDS-bounce coalesced epilogue + XCD-chunked swizzle.
// ---------------------------------------------------------------------------
__global__ __launch_bounds__(256) void gemm_qkv(
    const unsigned short* __restrict__ A,
    const unsigned short* __restrict__ Wqkv,
    const float* __restrict__ uball, const int* __restrict__ cidx,
    unsigned short* __restrict__ oq, unsigned short* __restrict__ ok,
    unsigned short* __restrict__ ov)
{
    const int tid = threadIdx.x;
    const int lin = blockIdx.y * gridDim.x + blockIdx.x;
    const int vb  = (lin & 7) * 375 + (lin >> 3);
    const int n0 = (vb % 12) * 128;   // 0..1535
    const int m0 = (vb / 12) * 128;
    const int lane = tid & 63, wid = tid >> 6;
    const int wm = (wid & 1) * 64, wn = (wid >> 1) * 64;

    __shared__ __align__(16) unsigned short sm[24576];
    __shared__ int cids[128];
    auto As = [&](int buf) { return (unsigned short(*)[32])(sm + buf * 4096); };
    auto Ws = [&](int buf) { return (unsigned short(*)[32])(sm + 12288 + buf * 4096); };
    auto bounce = (unsigned short(*)[136])sm;

    f32x4 acc[4][4];
#pragma unroll
    for (int i = 0; i < 4; ++i)
#pragma unroll
        for (int j = 0; j < 4; ++j) acc[i][j] = (f32x4){0.f, 0.f, 0.f, 0.f};

    const unsigned short* gA0 = &A[(size_t)(m0 + wid * 16 + (lane >> 2)) * EDIM + (lane & 3) * 8];
    const unsigned short* gA1 = gA0 + (size_t)64 * EDIM;
    const unsigned short* gW0 = &Wqkv[(size_t)(n0 + wid * 16 + (lane >> 2)) * EDIM + (lane & 3) * 8];
    const unsigned short* gW1 = gW0 + (size_t)64 * EDIM;
    const int frow = lane & 15, fk = (lane >> 4) * 8;

    auto stage = [&](int buf, int k0) {
        gload16(gA0 + k0, &As(buf)[wid * 16][0]);
        gload16(gA1 + k0, &As(buf)[64 + wid * 16][0]);
        gload16(gW0 + k0, &Ws(buf)[wid * 16][0]);
        gload16(gW1 + k0, &Ws(buf)[64 + wid * 16][0]);
    };
    stage(0, 0);
    stage(1, 32);

    const int nst = EDIM / 32;   // 8
    for (int t = 0; t < nst; ++t) {
        const int cur = t % 3;
        if (t < nst - 1) asm volatile("s_waitcnt vmcnt(4)" ::: "memory");
        else             asm volatile("s_waitcnt vmcnt(0)" ::: "memory");
        __builtin_amdgcn_s_barrier();
        __builtin_amdgcn_sched_barrier(0);
        if (t + 2 < nst) stage((t + 2) % 3, (t + 2) * 32);
        short8 af[4], wf[4];
#pragma unroll
        for (int mi = 0; mi < 4; ++mi)
            af[mi] = *(const short8*)&As(cur)[wm + mi * 16 + frow][fk];
#pragma unroll
        for (int ni = 0; ni < 4; ++ni)
            wf[ni] = *(const short8*)&Ws(cur)[wn + ni * 16 + frow][fk];
#pragma unroll
        for (int mi = 0; mi < 4; ++mi)
#pragma unroll
            for (int ni = 0; ni < 4; ++ni)
                acc[mi][ni] = __builtin_amdgcn_mfma_f32_16x16x32_bf16(
                    af[mi], wf[ni], acc[mi][ni], 0, 0, 0);
    }

    // ---- epilogue: bounce through LDS for coalesced stores ----
    const int z = n0 >> 9;               // 0=q 1=k 2=v
    const int b0 = m0 / NROWS;
    const int split = (b0 + 1) * NROWS;
    const int b1 = (split <= m0 + 127) ? b0 + 1 : b0;
    float ub0[4], ub1[4];
#pragma unroll
    for (int ni = 0; ni < 4; ++ni) {
        const int np = n0 + wn + ni * 16 + frow;
        ub0[ni] = uball[(size_t)b0 * NQKV + np];
        ub1[ni] = uball[(size_t)b1 * NQKV + np];
    }
    __syncthreads();
    if (z != 0 && tid < 128) {
        const int m = m0 + tid;
        const int b = (m >= split) ? b1 : b0;
        cids[tid] = cidx[b * 512 + (m - b * NROWS + 1)];
    }
#pragma unroll
    for (int mi = 0; mi < 4; ++mi)
#pragma unroll
        for (int r = 0; r < 4; ++r) {
            const int ml = wm + mi * 16 + (lane >> 4) * 4 + r;
            const bool hi = (m0 + ml >= split);
#pragma unroll
            for (int ni = 0; ni < 4; ++ni)
                bounce[ml][wn + ni * 16 + frow] =
                    f2bf(acc[mi][ni][r] + (hi ? ub1[ni] : ub0[ni]));
        }
    __syncthreads();

    const int h0 = (n0 & 511) >> 6;
    if (z == 0) {
        const int row = tid >> 1, half = tid & 1;
        const int m = m0 + row;
        const int b = (m >= split) ? b1 : b0;
        const int l = m - b * NROWS + 1;
        unsigned short* dst = &oq[(((size_t)b * HEADS + h0 + half) * LFULL + l) * HD];
        const unsigned short* src = &bounce[row][half * 64];
#pragma unroll
        for (int j = 0; j < 8; ++j)
            *(uint4*)(dst + j * 8) = *(const uint4*)(src + j * 8);
    } else if (z == 1) {
        const int row = tid >> 1, half = tid & 1;
        const int c = cids[row];
        if (c >= 0) {
            const int m = m0 + row;
            const int b = (m >= split) ? b1 : b0;
            unsigned short* dst = &ok[(((size_t)b * HEADS + h0 + half) * CMAX + c) * HD];
            const unsigned short* src = &bounce[row][half * 64];
#pragma unroll
            for (int j = 0; j < 8; ++j)
                *(uint4*)(dst + j * 8) = *(const uint4*)(src + j * 8);
        }
    } else {
        const int col = tid & 127, mh = tid >> 7;
        const int hh = h0 + (col >> 6), dd = col & 63;
        for (int mm = 0; mm < 64; ++mm) {
            const int row = mh * 64 + mm;
            const int c = cids[row];
            if (c >= 0) {
                const int m = m0 + row;
                const int b = (m >= split) ? b1 : b0;
                ov[((size_t)b * HEADS + hh) * (size_t)(HD * CMAX)
                   + (size_t)dd * CMAX + c] = bounce[row][col];
            }
        }
    }
}

// ---------------------------------------------------------------------------
// Generic bf16 GEMM (counted-vmcnt 3-buffer, stage-after-barrier) + XCD
// swizzle. MODE 1 (Wo): +bias, bf16 out, LN partials. MODE 2 (W1g): inline
// LN stats, LN-folded gelu + W2 dot.
// ---------------------------------------------------------------------------
template <int MODE>
__global__ __launch_bounds__(256) void gemm_bf16(
    const unsigned short* __restrict__ A,
    const unsigned short* __restrict__ W,
    const float* __restrict__ bias, void* __restrict__ outp,
    const float* __restrict__ W2, float* __restrict__ part,
    const float* __restrict__ rowpart, const float2* __restrict__ c1c2)
{
    const int tid = threadIdx.x;
    const int lin = blockIdx.y * gridDim.x + blockIdx.x;
    const int vb  = (lin & 7) * 125 + (lin >> 3);
    const int n0 = (vb % 4) * 128;
    const int m0 = (vb / 4) * 128;
    const int lane = tid & 63, wid = tid >> 6;
    const int wm = (wid & 1) * 64, wn = (wid >> 1) * 64;

    __shared__ unsigned short As[3][128][32];
    __shared__ unsigned short Ws[3][128][32];
    __shared__ float2 smusr[128];

    f32x4 acc[4][4];
#pragma unroll
    for (int i = 0; i < 4; ++i)
#pragma unroll
        for (int j = 0; j < 4; ++j) acc[i][j] = (f32x4){0.f, 0.f, 0.f, 0.f};

    const unsigned short* gA0 = &A[(size_t)(m0 + wid * 16 + (lane >> 2)) * DDIM + (lane & 3) * 8];
    const unsigned short* gA1 = gA0 + (size_t)64 * DDIM;
    const unsigned short* gW0 = &W[(size_t)(n0 + wid * 16 + (lane >> 2)) * DDIM + (lane & 3) * 8];
    const unsigned short* gW1 = gW0 + (size_t)64 * DDIM;
    const int frow = lane & 15, fk = (lane >> 4) * 8;

    auto stage = [&](int buf, int k0) {
        gload16(gA0 + k0, &As[buf][wid * 16][0]);
        gload16(gA1 + k0, &As[buf][64 + wid * 16][0]);
        gload16(gW0 + k0, &Ws[buf][wid * 16][0]);
        gload16(gW1 + k0, &Ws[buf][64 + wid * 16][0]);
    };
    stage(0, 0);
    stage(1, 32);

    const int nst = DDIM / 32;   // 16
    for (int t = 0; t < nst; ++t) {
        const int cur = t % 3;
        if (t < nst - 1) asm volatile("s_waitcnt vmcnt(4)" ::: "memory");
        else             asm volatile("s_waitcnt vmcnt(0)" ::: "memory");
        __builtin_amdgcn_s_barrier();
        __builtin_amdgcn_sched_barrier(0);
        if (t + 2 < nst) stage((t + 2) % 3, (t + 2) * 32);
        short8 af[4], wf[4];
#pragma unroll
        for (int mi = 0; mi < 4; ++mi)
            af[mi] = *(const short8*)&As[cur][wm + mi * 16 + frow][fk];
#pragma unroll
        for (int ni = 0; ni < 4; ++ni)
            wf[ni] = *(const short8*)&Ws[cur][wn + ni * 16 + frow][fk];
#pragma unroll
        for (int mi = 0; mi < 4; ++mi)
#pragma unroll
            for (int ni = 0; ni < 4; ++ni)
                acc[mi][ni] = __builtin_amdgcn_mfma_f32_16x16x32_bf16(
                    af[mi], wf[ni], acc[mi][ni], 0, 0, 0);
    }

    const int slot = (n0 >> 7) * 2 + (wn >> 6);   // 0..7
    if (MODE == 1) {
        float bv4[4];
#pragma unroll
        for (int ni = 0; ni < 4; ++ni) bv4[ni] = bias[n0 + wn + ni * 16 + frow];
#pragma unroll
        for (int mi = 0; mi < 4; ++mi)
#pragma unroll
            for (int r = 0; r < 4; ++r) {
                const int m = m0 + wm + mi * 16 + (lane >> 4) * 4 + r;
                float s1 = 0.f, s2 = 0.f;
#pragma unroll
                for (int ni = 0; ni < 4; ++ni) {
                    const float v = acc[mi][ni][r] + bv4[ni];
                    s1 += v; s2 += v * v;
                    ((unsigned short*)outp)[(size_t)m * DDIM + n0 + wn + ni * 16 + frow]
                        = f2bf(v);
                }
                s1 += __shfl_xor(s1, 1, 64); s2 += __shfl_xor(s2, 1, 64);
                s1 += __shfl_xor(s1, 2, 64); s2 += __shfl_xor(s2, 2, 64);
                s1 += __shfl_xor(s1, 4, 64); s2 += __shfl_xor(s2, 4, 64);
                s1 += __shfl_xor(s1, 8, 64); s2 += __shfl_xor(s2, 8, 64);
                if (frow == 0) {
                    part[((size_t)m << 4) + slot * 2]     = s1;
                    part[((size_t)m << 4) + slot * 2 + 1] = s2;
                }
            }
    } else {
        if (tid < 128) {
            const float* pp = rowpart + ((size_t)(m0 + tid) << 4);
            float s1 = 0.f, s2 = 0.f;
#pragma unroll
            for (int i = 0; i < 8; ++i) { s1 += pp[i * 2]; s2 += pp[i * 2 + 1]; }
            const float mu = s1 * (1.0f / DDIM);
            const float var = s2 * (1.0f / DDIM) - mu * mu;
            smusr[tid] = make_float2(mu, rsqrtf(var + 1e-5f));
        }
        float w2v[4], cb[4], c2v[4];
#pragma unroll
        for (int ni = 0; ni < 4; ++ni) {
            const int n = n0 + wn + ni * 16 + frow;
            w2v[ni] = W2[n];
            const float2 cc = c1c2[n];
            cb[ni]  = cc.x + bias[n];
            c2v[ni] = cc.y;
        }
        __syncthreads();
#pragma unroll
        for (int mi = 0; mi < 4; ++mi)
#pragma unroll
            for (int r = 0; r < 4; ++r) {
                const int ml = wm + mi * 16 + (lane >> 4) * 4 + r;
                const float2 ms = smusr[ml];
                float s = 0.f;
#pragma unroll
                for (int ni = 0; ni < 4; ++ni)
                    s += gelu_exact(ms.y * (acc[mi][ni][r] - ms.x * c2v[ni]) + cb[ni])
                         * w2v[ni];
                s += __shfl_xor(s, 1, 64);
                s += __shfl_xor(s, 2, 64);
                s += __shfl_xor(s, 4, 64);
                s += __shfl_xor(s, 8, 64);
                if (frow == 0)
                    part[(size_t)(m0 + ml) * 8 + slot] = s;
            }
    }
}

// ---------------------------------------------------------------------------
// Final reduction: out[m] = b2 + sum of 8 partials.
// ---------------------------------------------------------------------------
__global__ __launch_bounds__(256) void w2red_kernel(
    const float* __restrict__ part, const float* __restrict__ b2,
    float* __restrict__ out)
{
    const int m = blockIdx.x * 256 + threadIdx.x;
    if (m >= MTOT) return;
    const float* p = part + (size_t)m * 8;
    float s = b2[0];
#pragma unroll
    for (int i = 0; i < 8; ++i) s += p[i];
    out[m] = s;
}

// ---------------------------------------------------------------------------
// Attention v7: row-packed 32-row blocks, per-row key-count mask, fused exp,
// XCD-chunked swizzle (8192 = 8 x 1024).
// ---------------------------------------------------------------------------
__global__ __launch_bounds__(256) void attn_mfma(
    const unsigned short* __restrict__ qx, const unsigned short* __restrict__ kc,
    const unsigned short* __restrict__ vc, const int* __restrict__ cnt,
    unsigned short* __restrict__ outb)
{
    const int lin = blockIdx.x + NRB * (blockIdx.y + HEADS * blockIdx.z);
    const int vbk = (lin & 7) * (NRB * HEADS * BATCH / 8) + (lin >> 3);
    const int rbk = vbk % NRB;
    const int h   = (vbk / NRB) % HEADS;
    const int b   = vbk / (NRB * HEADS);
    const int g0  = rbk * RB;

    const int tid = threadIdx.x, lane = tid & 63, w = tid >> 6;

    __shared__ __align__(16) unsigned short scb[RB][520];
    __shared__ float rsw[4][RB];
    __shared__ int snck[RB];

    const int frow = lane & 15, fk = (lane >> 4) * 8;
    const size_t bh = (size_t)b * HEADS + h;
    const unsigned short* kbase = kc + bh * (CMAX * HD);
    const unsigned short* vbase = vc + bh * (HD * CMAX);

    if (tid < RB) {
        const int s = (g0 + tid >= NROWS ? NROWS - 1 : g0 + tid) / KPS;
        snck[tid] = cnt[b * 32 + s];
    }

    short8 qf[2][2];
#pragma unroll
    for (int mi = 0; mi < 2; ++mi) {
        const int qrow = g0 + mi * 16 + frow;
#pragma unroll
        for (int ks = 0; ks < 2; ++ks) {
            short8 v = {};
            if (qrow < NROWS)
                v = *(const short8*)&qx[(bh * LFULL + qrow + 1) * HD + ks * 32 + fk];
            qf[mi][ks] = v;
        }
    }
    __syncthreads();

    int nck8[2][4];
#pragma unroll
    for (int mi = 0; mi < 2; ++mi)
#pragma unroll
        for (int r = 0; r < 4; ++r)
            nck8[mi][r] = snck[mi * 16 + (lane >> 4) * 4 + r];
    const int nmax = snck[RB - 1];
    const int NT = (nmax + 63) >> 6;

    f32x4 rsum[2];
    rsum[0] = (f32x4){0.f, 0.f, 0.f, 0.f};
    rsum[1] = (f32x4){0.f, 0.f, 0.f, 0.f};
    for (int t = 0; t < NT; ++t) {
        const int key = (t << 6) + w * 16 + frow;
        const unsigned short* kr = kbase + (size_t)key * HD;
        const short8 kf0 = *(const short8*)(kr + fk);
        const short8 kf1 = *(const short8*)(kr + 32 + fk);
        f32x4 s2[2];
#pragma unroll
        for (int mi = 0; mi < 2; ++mi) {
            s2[mi] = (f32x4){0.f, 0.f, 0.f, 0.f};
            s2[mi] = __builtin_amdgcn_mfma_f32_16x16x32_bf16(qf[mi][0], kf0, s2[mi], 0, 0, 0);
            s2[mi] = __builtin_amdgcn_mfma_f32_16x16x32_bf16(qf[mi][1], kf1, s2[mi], 0, 0, 0);
        }
#pragma unroll
        for (int mi = 0; mi < 2; ++mi)
#pragma unroll
            for (int r = 0; r < 4; ++r) {
                const int row = mi * 16 + (lane >> 4) * 4 + r;
                const float p = (key < nck8[mi][r]) ? __expf(s2[mi][r] * 0.125f) : 0.f;
                rsum[mi][r] += p;
                scb[row][key] = f2bf(p);
            }
    }
#pragma unroll
    for (int mi = 0; mi < 2; ++mi)
#pragma unroll
        for (int r = 0; r < 4; ++r) {
            float v = rsum[mi][r];
            v += __shfl_xor(v, 1, 64);
            v += __shfl_xor(v, 2, 64);
            v += __shfl_xor(v, 4, 64);
            v += __shfl_xor(v, 8, 64);
            if (frow == 0)
                rsw[w][mi * 16 + (lane >> 4) * 4 + r] = v;
        }
    __syncthreads();

    f32x4 po[2];
    po[0] = (f32x4){0.f, 0.f, 0.f, 0.f};
    po[1] = (f32x4){0.f, 0.f, 0.f, 0.f};
    const unsigned short* vrow = vbase + (size_t)(w * 16 + frow) * CMAX;
    for (int t = 0; t < NT; ++t) {
#pragma unroll
        for (int ks = 0; ks < 2; ++ks) {
            const int kb0 = (t << 6) + ks * 32 + fk;
            const short8 vf = *(const short8*)(vrow + kb0);
#pragma unroll
            for (int mi = 0; mi < 2; ++mi) {
                const short8 pf = *(const short8*)&scb[mi * 16 + frow][kb0];
                po[mi] = __builtin_amdgcn_mfma_f32_16x16x32_bf16(pf, vf, po[mi], 0, 0, 0);
            }
        }
    }

#pragma unroll
    for (int mi = 0; mi < 2; ++mi)
#pragma unroll
        for (int r = 0; r < 4; ++r) {
            const int row = mi * 16 + (lane >> 4) * 4 + r;
            const int m = g0 + row;
            if (m < NROWS) {
                const float inv = 1.0f / (rsw[0][row] + rsw[1][row]
                                        + rsw[2][row] + rsw[3][row]);
                outb[((size_t)b * NROWS + m) * DDIM
                     + h * HD + w * 16 + frow] = f2bf(po[mi][r] * inv);
            }
        }
}

// ---------------------------------------------------------------------------
extern "C" void kernel_launch(void* const* d_in, const int* in_sizes, int n_in,
                              void* d_out, int out_size, void* d_ws, size_t ws_size,
                              hipStream_t stream)
{
    const float* item = (const float*)d_in[0];
    const float* user = (const float*)d_in[1];
    const int*   resp = (const int*)d_in[2];
    const float* Wq = (const float*)d_in[3];  const float* bq = (const float*)d_in[4];
    const float* Wk = (const float*)d_in[5];  const float* bk = (const float*)d_in[6];
    const float* Wv = (const float*)d_in[7];  const float* bv = (const float*)d_in[8];
    const float* Wo = (const float*)d_in[9];  const float* bo = (const float*)d_in[10];
    const float* lng = (const float*)d_in[11]; const float* lnb = (const float*)d_in[12];
    const float* W1 = (const float*)d_in[13]; const float* b1 = (const float*)d_in[14];
    const float* W2 = (const float*)d_in[15]; const float* b2 = (const float*)d_in[16];
    float* out = (float*)d_out;

    char* p = (char*)d_ws;
    auto alloc = [&](size_t bytes) { char* r = p; p += (bytes + 255) & ~(size_t)255; return r; };
    const size_t NITEM = (size_t)BATCH * NROWS * EDIM;
    const size_t NW    = (size_t)DDIM * DDIM;
    const size_t NQ    = (size_t)BATCH * HEADS * LFULL * HD;
    const size_t NC    = (size_t)BATCH * HEADS * CMAX * HD;
    const size_t NMD   = (size_t)MTOT * DDIM;
    const size_t PAD   = 8192;

    unsigned short* itemb  = (unsigned short*)alloc(NITEM * 2);
    unsigned short* Wqkvb  = (unsigned short*)alloc((size_t)NQKV * EDIM * 2);
    unsigned short* Wob    = (unsigned short*)alloc(NW * 2);
    unsigned short* W1gb   = (unsigned short*)alloc(NW * 2);
    unsigned short* qb     = (unsigned short*)alloc(NQ * 2 + PAD);
    unsigned short* kcb    = (unsigned short*)alloc(NC * 2 + PAD);
    unsigned short* vcb    = (unsigned short*)alloc(NC * 2 + PAD);
    unsigned short* aob    = (unsigned short*)alloc(NMD * 2);
    unsigned short* fb16   = (unsigned short*)alloc(NMD * 2);
    float*  uball  = (float*)alloc((size_t)BATCH * NQKV * 4);
    float*  part   = (float*)alloc((size_t)MTOT * 8 * 4);
    float*  rowpart= (float*)alloc((size_t)MTOT * 16 * 4);
    float2* c1c2   = (float2*)alloc((size_t)DDIM * 8);
    int* cidx    = (int*)alloc((size_t)BATCH * 512 * 4);
    int* cnt     = (int*)alloc((size_t)BATCH * 32 * 4);

    PrepArgs pa;
    pa.item = item; pa.user = user; pa.resp = resp;
    pa.Wq = Wq; pa.bq = bq; pa.Wk = Wk; pa.bk = bk; pa.Wv = Wv; pa.bv = bv;
    pa.Wo = Wo; pa.W1 = W1; pa.lng = lng; pa.lnb = lnb;
    pa.itemb = itemb; pa.Wqkvb = Wqkvb; pa.Wob = Wob;
    pa.W1gb = W1gb; pa.c1c2 = c1c2;
    pa.cidx = cidx; pa.cnt = cnt; pa.uball = uball;
    pa.qb = qb; pa.kc = kcb; pa.vc = vcb;
    prep_all<<<dim3(PREP_TOTAL), 256, 0, stream>>>(pa);

    gemm_qkv<<<dim3(NQKV / 128, MTOT / 128), 256, 0, stream>>>(
        itemb, Wqkvb, uball, cidx, qb, kcb, vcb);

    attn_mfma<<<dim3(NRB, HEADS, BATCH), 256, 0, stream>>>(qb, kcb, vcb, cnt, aob);

    dim3 gg(DDIM / 128, MTOT / 128);
    gemm_bf16<1><<<gg, 256, 0, stream>>>(aob, Wob, bo, fb16, nullptr, rowpart,
                                         nullptr, nullptr);
    gemm_bf16<2><<<gg, 256, 0, stream>>>(fb16, W1gb, b1, nullptr, W2, part,
                                         rowpart, c1c2);
    w2red_kernel<<<dim3((MTOT + 255) / 256), 256, 0, stream>>>(part, b2, out);
}